// Round 4
// baseline (346.059 us; speedup 1.0000x reference)
//
#include <hip/hip_runtime.h>
#include <math.h>

#define XDIM 47764
#define HDIM 128
#define LDIM 8
#define VTDIM 3620
#define WDIM 32
#define RDIM 8
#define NDIM 512
#define RW 256            // W*R
#define DDIM 48276        // X + RW + 2H
#define FIXED 48148       // X + RW + H (rows of si independent of h_prev_layer)
#define ETDIM 395
#define EPSV 1e-8f

#define CHUNK 768
#define NCHUNK 63         // ceil(48148/768)
#define K1_COMPUTE (32 * NCHUNK)   // 2016
#define K1_COPY 512

// ws layout (float offsets)
#define OFF_PARTIAL 0          // 32*63*128 = 258048
#define OFF_WREC    262144     // 32*128*128 = 524288
#define OFF_FLAT    786432     // 1024
#define OFF_ERAW    787456     // 512
#define OFF_WW      787968     // 512
#define OFF_MEMNEW  788480     // 16384
#define OFF_CR      804864     // 4096
#define OFF_RM      808960     // 32
#define OFF_FW      808992     // 4096
#define OFF_BW      813088     // 4096

__device__ inline float sigm(float x) { return 1.f / (1.f + expf(-x)); }
__device__ inline float log_sigmoid(float x) {
    return (x >= 0.f) ? -log1pf(expf(-x)) : (x - log1pf(expf(x)));
}

// ---------------- K1: partial gate pre-activations + weight compaction ------
// Each wave's load instruction covers 2 CONSECUTIVE rows = 1 KB contiguous:
// lane = (rip, c4): rip = lane>>5 picks row d/d+1, c4 = lane&31 picks float4.
__global__ __launch_bounds__(256) void k1_partial(
    const float* __restrict__ x_in, const float* __restrict__ lrv,
    const float* __restrict__ hprev,
    const float* __restrict__ Wi, const float* __restrict__ Wf,
    const float* __restrict__ Wo, const float* __restrict__ Ws,
    float* __restrict__ ws)
{
    const int bid = blockIdx.x;
    const int t   = threadIdx.x;

    if (bid >= K1_COMPUTE) {
        // compaction: W*[l][FIXED+j][h] -> wrec[combo][j][h], 1 float4/thread
        int idx4  = (bid - K1_COMPUTE) * 256 + t;
        int flat  = idx4 << 2;
        int combo = flat >> 14;
        int rem   = flat & 16383;
        int j = rem >> 7, h = rem & 127;
        int g = combo >> 3, l = combo & 7;
        const float* Wg = (g == 0) ? Wi : (g == 1) ? Wf : (g == 2) ? Wo : Ws;
        float4 v = *reinterpret_cast<const float4*>(
            Wg + ((size_t)l * DDIM + FIXED + j) * HDIM + h);
        *reinterpret_cast<float4*>(ws + OFF_WREC + flat) = v;
        return;
    }

    const int combo = bid / NCHUNK;
    const int chunk = bid % NCHUNK;
    const int g = combo >> 3, l = combo & 7;
    const float* __restrict__ Wg = (g == 0) ? Wi : (g == 1) ? Wf : (g == 2) ? Wo : Ws;
    const int d0 = chunk * CHUNK;

    __shared__ float s_lds[CHUNK];
    for (int i = t; i < CHUNK; i += 256) {
        int d = d0 + i;
        float v = 0.f;
        if (d < XDIM)            v = x_in[d];
        else if (d < XDIM + RW)  v = lrv[d - XDIM];
        else if (d < FIXED)      v = hprev[l * HDIM + (d - XDIM - RW)];
        s_lds[i] = v;
    }
    __syncthreads();

    const int wave = t >> 6;        // 0..3, owns 192 contiguous rows
    const int lane = t & 63;
    const int rip  = lane >> 5;     // row-in-pair (0/1)
    const int c4   = lane & 31;     // float4 column
    const int rbase = wave * 192;

    // per-thread row sequence: rbase + 2*i + rip, i = 0..95
    const float* wp = Wg + ((size_t)l * DDIM + d0 + rbase + rip) * HDIM + (c4 << 2);

    float4 acc = make_float4(0.f, 0.f, 0.f, 0.f);

    if (chunk != NCHUNK - 1) {
        for (int i0 = 0; i0 < 96; i0 += 4) {
            // 4 wave-loads, each 1 KB fully contiguous; 4 KB run per group
            const float4 w0 = *reinterpret_cast<const float4*>(wp);
            const float4 w1 = *reinterpret_cast<const float4*>(wp + 256);
            const float4 w2 = *reinterpret_cast<const float4*>(wp + 512);
            const float4 w3 = *reinterpret_cast<const float4*>(wp + 768);
            wp += 1024;
            const int rr = rbase + 2 * i0 + rip;
            const float s0 = s_lds[rr];
            const float s1 = s_lds[rr + 2];
            const float s2 = s_lds[rr + 4];
            const float s3 = s_lds[rr + 6];
            acc.x += s0 * w0.x; acc.y += s0 * w0.y; acc.z += s0 * w0.z; acc.w += s0 * w0.w;
            acc.x += s1 * w1.x; acc.y += s1 * w1.y; acc.z += s1 * w1.z; acc.w += s1 * w1.w;
            acc.x += s2 * w2.x; acc.y += s2 * w2.y; acc.z += s2 * w2.z; acc.w += s2 * w2.w;
            acc.x += s3 * w3.x; acc.y += s3 * w3.y; acc.z += s3 * w3.z; acc.w += s3 * w3.w;
        }
    } else {
        // tail chunk: per-iteration guard (rows >= FIXED must not be touched)
        for (int i = 0; i < 96; ++i) {
            int d = d0 + rbase + 2 * i + rip;
            if (d < FIXED) {
                const float s = s_lds[rbase + 2 * i + rip];
                const float4 w = *reinterpret_cast<const float4*>(wp);
                acc.x += s * w.x; acc.y += s * w.y; acc.z += s * w.z; acc.w += s * w.w;
            }
            wp += 256;
        }
    }

    __shared__ float4 red[8][32];
    red[t >> 5][c4] = acc;
    __syncthreads();
    if (t < 32) {
        float4 s = red[0][t];
        #pragma unroll
        for (int q = 1; q < 8; ++q) {
            float4 v = red[q][t];
            s.x += v.x; s.y += v.y; s.z += v.z; s.w += v.w;
        }
        *reinterpret_cast<float4*>(ws + OFF_PARTIAL +
            ((size_t)(combo * NCHUNK + chunk)) * HDIM + (t << 2)) = s;
    }
}

// -------- K3: partial-reduce + bias, then sequential layer chain (1 block) --
__global__ __launch_bounds__(1024) void k3_recurrent(
    const float* __restrict__ bi, const float* __restrict__ bf,
    const float* __restrict__ bo, const float* __restrict__ bs,
    const float* __restrict__ old_states, float* __restrict__ ws,
    float* __restrict__ out)
{
    const int t = threadIdx.x;          // 0..1023
    const int g = t >> 8;               // gate 0..3
    const int q = (t >> 7) & 1;         // half of j-dim
    const int h = t & 127;

    __shared__ float fixed_s[32][128];  // 16 KB
    __shared__ float hp[128];
    __shared__ float gl[4][2][128];

    // zero d_out (for k45 atomics) and E_raw
    for (int i = t; i < VTDIM; i += 1024) out[i] = 0.f;
    if (t < 512) ws[OFF_ERAW + t] = 0.f;

    // reduce chunk partials + bias
    const float* bg = (g == 0) ? bi : (g == 1) ? bf : (g == 2) ? bo : bs;
    for (int l = q; l < LDIM; l += 2) {
        int combo = g * 8 + l;
        float acc = bg[l * HDIM + h];
        const float* P = ws + OFF_PARTIAL + (size_t)combo * NCHUNK * HDIM + h;
        for (int c = 0; c < NCHUNK; ++c) acc += P[c * HDIM];
        fixed_s[combo][h] = acc;
    }
    if (t < 128) hp[t] = 0.f;
    __syncthreads();

    for (int l = 0; l < LDIM; ++l) {
        int combo = g * 8 + l;
        float acc = (q == 0) ? fixed_s[combo][h] : 0.f;
        const float* wr = ws + OFF_WREC + (size_t)combo * 16384 + (q << 6) * 128 + h;
        #pragma unroll 8
        for (int j = 0; j < 64; ++j) acc += hp[(q << 6) + j] * wr[j * 128];
        gl[g][q][h] = acc;
        __syncthreads();
        if (t < 128) {
            float ig = sigm(gl[0][0][t] + gl[0][1][t]);
            float fg = sigm(gl[1][0][t] + gl[1][1][t]);
            float og = sigm(gl[2][0][t] + gl[2][1][t]);
            float ss = tanhf(gl[3][0][t] + gl[3][1][t]);
            float st = fg * old_states[l * HDIM + t] + ig * ss;
            float hn = og * tanhf(st);
            hp[t] = hn;
            ws[OFF_FLAT + l * HDIM + t] = hn;
        }
        __syncthreads();
    }
}

// ---------------- K45: flat@W_y -> d_out, flat@W_E -> E_raw ----------------
__global__ __launch_bounds__(256) void k45_out_E(
    const float* __restrict__ Wy, const float* __restrict__ We,
    float* __restrict__ dout, float* __restrict__ ws)
{
    const int blk = blockIdx.x, t = threadIdx.x;
    __shared__ float fl[128];
    if (blk < 120) {
        int vt = blk % 15, kc = blk / 15;
        if (t < 128) fl[t] = ws[OFF_FLAT + kc * 128 + t];
        __syncthreads();
        int v = vt * 256 + t;
        if (v < VTDIM) {
            float acc = 0.f;
            const float* Wp = Wy + (size_t)kc * 128 * VTDIM + v;
            #pragma unroll 8
            for (int k = 0; k < 128; ++k) acc += fl[k] * Wp[(size_t)k * VTDIM];
            atomicAdd(&dout[v], acc);
        }
    } else {
        int kc = blk - 120;
        if (t < 128) fl[t] = ws[OFF_FLAT + kc * 128 + t];
        __syncthreads();
        if (t < ETDIM) {
            float acc = 0.f;
            const float* Wp = We + (size_t)kc * 128 * ETDIM + t;
            #pragma unroll 8
            for (int k = 0; k < 128; ++k) acc += fl[k] * Wp[k * ETDIM];
            atomicAdd(&ws[OFF_ERAW + t], acc);
        }
    }
}

// ------ K6: E unpack + usage/alloc(rank-product) + write/memory/cr ---------
__global__ __launch_bounds__(512) void k6_small(
    const float* __restrict__ memory, const float* __restrict__ lrw,
    const float* __restrict__ lu, const float* __restrict__ lww,
    float* __restrict__ ws)
{
    const int t = threadIdx.x;
    const int lane = t & 63, wid = t >> 6;
    __shared__ float Es[400];
    __shared__ float rk[256], wk[32], er[32], wv[32], fgs[8], rs_s[8], rm[24], scal[3];
    __shared__ float u_s[512];
    __shared__ float wred[8];
    __shared__ float wred8[8][8];
    __shared__ float srk[8];

    if (t < ETDIM) Es[t] = ws[OFF_ERAW + t];
    __syncthreads();

    if (t < 256)                 rk[t] = Es[t];
    if (t >= 256 && t < 264)     rs_s[t - 256] = 1.f - log_sigmoid(Es[t]);
    if (t >= 264 && t < 296)     wk[t - 264] = Es[t];
    if (t == 296)                scal[0] = 1.f - log_sigmoid(Es[296]);   // write_strength
    if (t >= 297 && t < 329)     er[t - 297] = sigm(Es[t]);
    if (t >= 329 && t < 361)     wv[t - 329] = Es[t];
    if (t >= 361 && t < 369)     fgs[t - 361] = sigm(Es[t]);
    if (t == 369)                scal[1] = sigm(Es[369]);                // alloc_gate
    if (t == 370)                scal[2] = sigm(Es[370]);                // write_gate
    if (t >= 384 && t < 392) {                                          // read_modes
        int r = t - 384;
        float a = Es[371 + 3*r], b = Es[372 + 3*r], c = Es[373 + 3*r];
        float mx = fmaxf(a, fmaxf(b, c));
        float ea = expf(a - mx), eb = expf(b - mx), ec = expf(c - mx);
        float s = ea + eb + ec;
        rm[3*r] = ea / s; rm[3*r + 1] = eb / s; rm[3*r + 2] = ec / s;
    }
    __syncthreads();

    // usage
    float psi = 1.f;
    #pragma unroll
    for (int r = 0; r < 8; ++r) psi *= 1.f - fgs[r] * lrw[t * 8 + r];
    float ua = lu[t], ub = lww[t];
    float u_t = (ua + ub - ua * ub) * psi;
    u_s[t] = u_t;
    __syncthreads();

    // alloc[t] = (1-u_t) * prod over (u_j,j) lexicographically before (u_t,t)
    float prod = 1.f;
    for (int j = 0; j < 512; ++j) {
        float uj = u_s[j];
        bool before = (uj < u_t) || (uj == u_t && j < t);
        prod *= before ? uj : 1.f;
    }
    float alloc_t = (1.f - u_t) * prod;

    // write-key norm (every thread, broadcast reads)
    float s2 = 0.f;
    #pragma unroll
    for (int w = 0; w < 32; ++w) s2 += wk[w] * wk[w];
    float wkinv = 1.f / fmaxf(sqrtf(s2), EPSV);

    // content write score
    float mrow[32];
    float dotv = 0.f, nn = 0.f;
    #pragma unroll
    for (int w = 0; w < 32; ++w) {
        float m = memory[t * 32 + w];
        mrow[w] = m; dotv += m * wk[w]; nn += m * m;
    }
    float score = scal[0] * wkinv * dotv / fmaxf(sqrtf(nn), EPSV);
    float v = score;
    #pragma unroll
    for (int o = 32; o > 0; o >>= 1) v = fmaxf(v, __shfl_xor(v, o));
    if (lane == 0) wred[wid] = v;
    __syncthreads();
    float mx = wred[0];
    #pragma unroll
    for (int qq = 1; qq < 8; ++qq) mx = fmaxf(mx, wred[qq]);
    __syncthreads();
    float e = expf(score - mx);
    v = e;
    #pragma unroll
    for (int o = 32; o > 0; o >>= 1) v += __shfl_xor(v, o);
    if (lane == 0) wred[wid] = v;
    __syncthreads();
    float ssum = 0.f;
    #pragma unroll
    for (int qq = 0; qq < 8; ++qq) ssum += wred[qq];
    float cwv = e / ssum;

    float wwn = scal[2] * (scal[1] * alloc_t + (1.f - scal[1]) * cwv);
    ws[OFF_WW + t] = wwn;

    // memory_new + row norm
    float nn2 = 0.f;
    #pragma unroll
    for (int w = 0; w < 32; ++w) {
        float mn = mrow[w] * (1.f - wwn * er[w]) + wwn * wv[w];
        mrow[w] = mn; nn2 += mn * mn;
        ws[OFF_MEMNEW + t * 32 + w] = mn;
    }
    float inv2 = 1.f / fmaxf(sqrtf(nn2), EPSV);

    if (t < 8) {
        float s3 = 0.f;
        #pragma unroll
        for (int w = 0; w < 32; ++w) { float x = rk[w * 8 + t]; s3 += x * x; }
        srk[t] = rs_s[t] / fmaxf(sqrtf(s3), EPSV);
    }
    __syncthreads();

    // read content scores + softmax over n per head (shfl reductions)
    float sc[8];
    #pragma unroll
    for (int r = 0; r < 8; ++r) {
        float d2 = 0.f;
        #pragma unroll
        for (int w = 0; w < 32; ++w) d2 += mrow[w] * rk[w * 8 + r];
        sc[r] = srk[r] * inv2 * d2;
    }
    #pragma unroll
    for (int r = 0; r < 8; ++r) {
        float x = sc[r];
        #pragma unroll
        for (int o = 32; o > 0; o >>= 1) x = fmaxf(x, __shfl_xor(x, o));
        if (lane == 0) wred8[wid][r] = x;
    }
    __syncthreads();
    float mxr[8];
    #pragma unroll
    for (int r = 0; r < 8; ++r) {
        float m = wred8[0][r];
        #pragma unroll
        for (int qq = 1; qq < 8; ++qq) m = fmaxf(m, wred8[qq][r]);
        mxr[r] = m;
    }
    __syncthreads();
    float ex[8];
    #pragma unroll
    for (int r = 0; r < 8; ++r) {
        ex[r] = expf(sc[r] - mxr[r]);
        float x = ex[r];
        #pragma unroll
        for (int o = 32; o > 0; o >>= 1) x += __shfl_xor(x, o);
        if (lane == 0) wred8[wid][r] = x;
    }
    __syncthreads();
    #pragma unroll
    for (int r = 0; r < 8; ++r) {
        float sm = 0.f;
        #pragma unroll
        for (int qq = 0; qq < 8; ++qq) sm += wred8[qq][r];
        ws[OFF_CR + t * 8 + r] = ex[r] / sm;
    }
    if (t < 24) ws[OFF_RM + t] = rm[t];
}

// ---------------- K7: linkage fw/bw ---------------------------------------
__global__ __launch_bounds__(256) void k7_linkage(
    const float* __restrict__ linkage, const float* __restrict__ prec,
    const float* __restrict__ lrw, float* __restrict__ ws)
{
    __shared__ float lrw_s[4096];
    __shared__ float ww_s[512];
    __shared__ float red2[2048];
    const int t = threadIdx.x, blk = blockIdx.x;
    for (int i = t; i < 4096; i += 256) lrw_s[i] = lrw[i];
    for (int i = t; i < 512; i += 256)  ww_s[i] = ws[OFF_WW + i];
    __syncthreads();

    if (blk < 512) {
        const int i = blk;
        const float ww_i = ww_s[i];
        float facc[8] = {0,0,0,0,0,0,0,0};
        for (int j = t; j < 512; j += 256) {
            float Lm = (j == i) ? 0.f
                     : (1.f - ww_i - ww_s[j]) * linkage[(size_t)i * 512 + j] + ww_i * prec[j];
            #pragma unroll
            for (int r = 0; r < 8; ++r) facc[r] += Lm * lrw_s[j * 8 + r];
        }
        #pragma unroll
        for (int r = 0; r < 8; ++r) red2[t * 8 + r] = facc[r];
        __syncthreads();
        for (int s = 128; s > 0; s >>= 1) {
            if (t < s) {
                #pragma unroll
                for (int r = 0; r < 8; ++r) red2[t * 8 + r] += red2[(t + s) * 8 + r];
            }
            __syncthreads();
        }
        if (t < 8) ws[OFF_FW + i * 8 + t] = red2[t];
    } else {
        const int bb = blk - 512;
        const int ii = t & 63, p = t >> 6;
        const int i = bb * 64 + ii;
        const float ww_i = ww_s[i], prec_i = prec[i];
        float bacc[8] = {0,0,0,0,0,0,0,0};
        for (int j = p * 128; j < p * 128 + 128; ++j) {
            float lj  = linkage[(size_t)j * 512 + i];
            float wwj = ww_s[j];
            float Lm  = (j == i) ? 0.f : (1.f - wwj - ww_i) * lj + wwj * prec_i;
            #pragma unroll
            for (int r = 0; r < 8; ++r) bacc[r] += Lm * lrw_s[j * 8 + r];
        }
        #pragma unroll
        for (int r = 0; r < 8; ++r) red2[t * 8 + r] = bacc[r];
        __syncthreads();
        if (p == 0) {
            #pragma unroll
            for (int r = 0; r < 8; ++r) {
                float s = red2[t * 8 + r] + red2[(t + 64) * 8 + r]
                        + red2[(t + 128) * 8 + r] + red2[(t + 192) * 8 + r];
                ws[OFF_BW + i * 8 + r] = s;
            }
        }
    }
}

// ------- K8: rw -> rv (in-LDS, per-block) -> y += rv @ W_r -----------------
__global__ __launch_bounds__(256) void k8_read_out(
    const float* __restrict__ Wr, float* __restrict__ dout,
    const float* __restrict__ ws)
{
    __shared__ float mn_s[NDIM * 32];     // 64 KB
    __shared__ float rw_s[NDIM * 8];      // 16 KB
    __shared__ float rred[8][32][8];      // 8 KB
    __shared__ float rv_s[256];
    __shared__ float rm_s[24];
    const int t = threadIdx.x;

    for (int i = t; i < NDIM * 8; i += 256)   // 16384 floats as float4
        *reinterpret_cast<float4*>(mn_s + (i << 2)) =
            *reinterpret_cast<const float4*>(ws + OFF_MEMNEW + (i << 2));
    if (t < 24) rm_s[t] = ws[OFF_RM + t];
    __syncthreads();

    for (int idx = t; idx < 4096; idx += 256) {
        int r = idx & 7;
        rw_s[idx] = ws[OFF_BW + idx] * rm_s[r * 3]
                  + ws[OFF_CR + idx] * rm_s[r * 3 + 1]
                  + ws[OFF_FW + idx] * rm_s[r * 3 + 2];
    }
    __syncthreads();

    const int g = t >> 5, w = t & 31;
    float acc[8] = {0,0,0,0,0,0,0,0};
    for (int n = g * 64; n < g * 64 + 64; ++n) {
        float m = mn_s[n * 32 + w];
        #pragma unroll
        for (int r = 0; r < 8; ++r) acc[r] += m * rw_s[n * 8 + r];
    }
    #pragma unroll
    for (int r = 0; r < 8; ++r) rred[g][w][r] = acc[r];
    __syncthreads();
    {
        int w2 = t >> 3, r2 = t & 7;
        float s = 0.f;
        #pragma unroll
        for (int qq = 0; qq < 8; ++qq) s += rred[qq][w2][r2];
        rv_s[w2 * 8 + r2] = s;
    }
    __syncthreads();

    int v = blockIdx.x * 256 + t;
    if (v < VTDIM) {
        float acc2 = 0.f;
        const float* Wp = Wr + v;
        #pragma unroll 8
        for (int k = 0; k < 256; ++k) acc2 += rv_s[k] * Wp[(size_t)k * VTDIM];
        dout[v] += acc2;
    }
}

extern "C" void kernel_launch(void* const* d_in, const int* in_sizes, int n_in,
                              void* d_out, int out_size, void* d_ws, size_t ws_size,
                              hipStream_t stream)
{
    const float* x_in   = (const float*)d_in[0];
    const float* Wi     = (const float*)d_in[1];
    const float* bi     = (const float*)d_in[2];
    const float* Wf     = (const float*)d_in[3];
    const float* bf     = (const float*)d_in[4];
    const float* Wo     = (const float*)d_in[5];
    const float* bo     = (const float*)d_in[6];
    const float* Wss    = (const float*)d_in[7];
    const float* bs     = (const float*)d_in[8];
    const float* Wy     = (const float*)d_in[9];
    const float* We     = (const float*)d_in[10];
    const float* Wr     = (const float*)d_in[11];
    const float* memory = (const float*)d_in[12];
    const float* lrv    = (const float*)d_in[13];
    const float* hprev  = (const float*)d_in[14];
    const float* old_st = (const float*)d_in[15];
    const float* prec   = (const float*)d_in[16];
    const float* linkage= (const float*)d_in[17];
    const float* lrw    = (const float*)d_in[18];
    const float* lu     = (const float*)d_in[19];
    const float* lww    = (const float*)d_in[20];
    float* out = (float*)d_out;
    float* ws  = (float*)d_ws;

    k1_partial<<<K1_COMPUTE + K1_COPY, 256, 0, stream>>>(x_in, lrv, hprev, Wi, Wf, Wo, Wss, ws);
    k3_recurrent<<<1, 1024, 0, stream>>>(bi, bf, bo, bs, old_st, ws, out);
    k45_out_E<<<128, 256, 0, stream>>>(Wy, We, out, ws);
    k6_small<<<1, 512, 0, stream>>>(memory, lrw, lu, lww, ws);
    k7_linkage<<<520, 256, 0, stream>>>(linkage, prec, lrw, ws);
    k8_read_out<<<15, 256, 0, stream>>>(Wr, out, ws);
}

// Round 5
// 322.304 us; speedup vs baseline: 1.0737x; 1.0737x over previous
//
#include <hip/hip_runtime.h>
#include <math.h>

#define XDIM 47764
#define HDIM 128
#define LDIM 8
#define VTDIM 3620
#define WDIM 32
#define RDIM 8
#define NDIM 512
#define RW 256            // W*R
#define DDIM 48276        // X + RW + 2H
#define FIXED 48148       // X + RW + H (rows of si independent of h_prev_layer)
#define ETDIM 395
#define EPSV 1e-8f

#define CHUNK 768
#define NCHUNK 63         // ceil(48148/768)
#define TILE 16           // rows per DMA tile = 8 KB
#define DEPTH 4           // tile ring buffer depth
#define NT 48             // CHUNK / TILE
#define K1_COMPUTE (32 * NCHUNK)   // 2016
#define K1_COPYB 128               // wrec copy blocks

// ws layout (float offsets)
#define OFF_FIXED   258048     // 32*128 gate preacts (atomic accum, memset 0)
#define OFF_WREC    262144     // 32*128*128 = 524288
#define OFF_FLAT    786432     // 1024
#define OFF_ERAW    787456     // 512
#define OFF_WW      787968     // 512
#define OFF_MEMNEW  788480     // 16384
#define OFF_CR      804864     // 4096
#define OFF_RM      808960     // 32
#define OFF_FW      808992     // 4096
#define OFF_BW      813088     // 4096

__device__ inline float sigm(float x) { return 1.f / (1.f + expf(-x)); }
__device__ inline float log_sigmoid(float x) {
    return (x >= 0.f) ? -log1pf(expf(-x)) : (x - log1pf(expf(x)));
}

__device__ __forceinline__ void gl_lds16(const float* g, float* l) {
    __builtin_amdgcn_global_load_lds(
        (const __attribute__((address_space(1))) void*)g,
        (__attribute__((address_space(3))) void*)l,
        16, 0, 0);
}

// ---------------- K1: DMA-staged gate pre-activations + weight compaction ---
__global__ __launch_bounds__(256) void k1_partial(
    const float* __restrict__ x_in, const float* __restrict__ lrv,
    const float* __restrict__ hprev,
    const float* __restrict__ Wi, const float* __restrict__ Wf,
    const float* __restrict__ Wo, const float* __restrict__ Ws,
    float* __restrict__ ws, float* __restrict__ out)
{
    const int bid = blockIdx.x;
    const int t   = threadIdx.x;

    if (bid >= K1_COMPUTE) {
        // compaction: W*[l][FIXED+j][h] -> wrec[combo][j][h]
        int cb = bid - K1_COMPUTE;
        #pragma unroll
        for (int r = 0; r < 4; ++r) {
            int idx4  = cb * 1024 + r * 256 + t;
            int flat  = idx4 << 2;
            int combo = flat >> 14;
            int rem   = flat & 16383;
            int j = rem >> 7, h = rem & 127;
            int g = combo >> 3, l = combo & 7;
            const float* Wg = (g == 0) ? Wi : (g == 1) ? Wf : (g == 2) ? Wo : Ws;
            float4 v = *reinterpret_cast<const float4*>(
                Wg + ((size_t)l * DDIM + FIXED + j) * HDIM + h);
            *reinterpret_cast<float4*>(ws + OFF_WREC + flat) = v;
        }
        if (cb == 0) { ws[OFF_ERAW + t] = 0.f; ws[OFF_ERAW + 256 + t] = 0.f; }
        else if (cb == 1) {
            #pragma unroll
            for (int r = 0; r < 8; ++r) out[r * 256 + t] = 0.f;
        } else if (cb == 2) {
            #pragma unroll
            for (int r = 0; r < 7; ++r) {
                int v = 2048 + r * 256 + t;
                if (v < VTDIM) out[v] = 0.f;
            }
        }
        return;
    }

    const int combo = bid / NCHUNK;
    const int chunk = bid % NCHUNK;
    const int g = combo >> 3, l = combo & 7;
    const float* __restrict__ Wg = (g == 0) ? Wi : (g == 1) ? Wf : (g == 2) ? Wo : Ws;
    const int d0 = chunk * CHUNK;

    __shared__ float act[CHUNK];                 // 3 KB
    __shared__ float wbuf[DEPTH][TILE * HDIM];   // 32 KB
    __shared__ float4 red[8][32];                // 4 KB

    for (int i = t; i < CHUNK; i += 256) {
        int d = d0 + i;
        float v = 0.f;
        if (d < XDIM)            v = x_in[d];
        else if (d < XDIM + RW)  v = lrv[d - XDIM];
        else if (d < FIXED)      v = hprev[l * HDIM + (d - XDIM - RW)];
        act[i] = v;
    }

    const int nt = (chunk == NCHUNK - 1) ? 34 : NT;   // tail: 532 valid rows
    const float* gchunk = Wg + ((size_t)l * DDIM + d0) * HDIM;
    const int wv  = t >> 6, ln = t & 63;
    const int off = wv * 512 + ln * 4;   // floats: wave wv covers 2 KB (2 insts)

    // prologue: issue tiles 0..DEPTH-2
    #pragma unroll
    for (int pp = 0; pp < DEPTH - 1; ++pp) {
        const float* gb = gchunk + (size_t)pp * TILE * HDIM;
        float* lb = &wbuf[pp][0];
        gl_lds16(gb + off, lb + off);
        gl_lds16(gb + off + 256, lb + off + 256);
    }

    const int c4 = t & 31;    // float4 column
    const int p  = t >> 5;    // slice 0..7 -> rows 2p, 2p+1 of each tile
    float4 acc = make_float4(0.f, 0.f, 0.f, 0.f);

    for (int i = 0; i < nt; ++i) {
        __syncthreads();   // drains DMA: tile i (issued >=2 iters ago) ready
        if (i + DEPTH - 1 < nt) {
            // fills slot (i-1)&3: computed last iter, all waves past it
            const float* gb = gchunk + (size_t)(i + DEPTH - 1) * TILE * HDIM;
            float* lb = &wbuf[(i + DEPTH - 1) & (DEPTH - 1)][0];
            gl_lds16(gb + off, lb + off);
            gl_lds16(gb + off + 256, lb + off + 256);
        }
        const float* wb = &wbuf[i & (DEPTH - 1)][0];
        const int rr = (i << 4) + (p << 1);
        const float a0 = act[rr];
        const float a1 = act[rr + 1];
        const float4 w0 = *reinterpret_cast<const float4*>(wb + (p << 1) * HDIM + (c4 << 2));
        const float4 w1 = *reinterpret_cast<const float4*>(wb + ((p << 1) + 1) * HDIM + (c4 << 2));
        acc.x += a0 * w0.x + a1 * w1.x;
        acc.y += a0 * w0.y + a1 * w1.y;
        acc.z += a0 * w0.z + a1 * w1.z;
        acc.w += a0 * w0.w + a1 * w1.w;
    }

    red[p][c4] = acc;
    __syncthreads();
    if (t < 32) {
        float4 s = red[0][t];
        #pragma unroll
        for (int q = 1; q < 8; ++q) {
            float4 v = red[q][t];
            s.x += v.x; s.y += v.y; s.z += v.z; s.w += v.w;
        }
        float* fx = ws + OFF_FIXED + combo * HDIM + (t << 2);
        atomicAdd(fx + 0, s.x);
        atomicAdd(fx + 1, s.y);
        atomicAdd(fx + 2, s.z);
        atomicAdd(fx + 3, s.w);
    }
}

// -------- K3: bias + sequential layer chain (1 block) ----------------------
__global__ __launch_bounds__(1024) void k3_recurrent(
    const float* __restrict__ bi, const float* __restrict__ bf,
    const float* __restrict__ bo, const float* __restrict__ bs,
    const float* __restrict__ old_states, float* __restrict__ ws)
{
    const int t = threadIdx.x;          // 0..1023
    const int g = t >> 8;               // gate 0..3
    const int q = (t >> 7) & 1;         // half of j-dim
    const int h = t & 127;

    __shared__ float hp[128];
    __shared__ float gl[4][2][128];

    float fx[8];
    const float* bg = (g == 0) ? bi : (g == 1) ? bf : (g == 2) ? bo : bs;
    if (q == 0) {
        #pragma unroll
        for (int l = 0; l < LDIM; ++l)
            fx[l] = ws[OFF_FIXED + (g * 8 + l) * HDIM + h] + bg[l * HDIM + h];
    }
    if (t < 128) hp[t] = 0.f;
    __syncthreads();

    for (int l = 0; l < LDIM; ++l) {
        int combo = g * 8 + l;
        float acc = (q == 0) ? fx[l] : 0.f;
        const float* wr = ws + OFF_WREC + (size_t)combo * 16384 + (q << 6) * 128 + h;
        #pragma unroll 8
        for (int j = 0; j < 64; ++j) acc += hp[(q << 6) + j] * wr[j * 128];
        gl[g][q][h] = acc;
        __syncthreads();
        if (t < 128) {
            float ig = sigm(gl[0][0][t] + gl[0][1][t]);
            float fg = sigm(gl[1][0][t] + gl[1][1][t]);
            float og = sigm(gl[2][0][t] + gl[2][1][t]);
            float ss = tanhf(gl[3][0][t] + gl[3][1][t]);
            float st = fg * old_states[l * HDIM + t] + ig * ss;
            float hn = og * tanhf(st);
            hp[t] = hn;
            ws[OFF_FLAT + l * HDIM + t] = hn;
        }
        __syncthreads();
    }
}

// ---------------- K45: flat@W_y -> d_out, flat@W_E -> E_raw ----------------
__global__ __launch_bounds__(256) void k45_out_E(
    const float* __restrict__ Wy, const float* __restrict__ We,
    float* __restrict__ dout, float* __restrict__ ws)
{
    const int blk = blockIdx.x, t = threadIdx.x;
    __shared__ float fl[128];
    if (blk < 120) {
        int vt = blk % 15, kc = blk / 15;
        if (t < 128) fl[t] = ws[OFF_FLAT + kc * 128 + t];
        __syncthreads();
        int v = vt * 256 + t;
        if (v < VTDIM) {
            float acc = 0.f;
            const float* Wp = Wy + (size_t)kc * 128 * VTDIM + v;
            #pragma unroll 8
            for (int k = 0; k < 128; ++k) acc += fl[k] * Wp[(size_t)k * VTDIM];
            atomicAdd(&dout[v], acc);
        }
    } else {
        int kc = blk - 120;
        if (t < 128) fl[t] = ws[OFF_FLAT + kc * 128 + t];
        __syncthreads();
        if (t < ETDIM) {
            float acc = 0.f;
            const float* Wp = We + (size_t)kc * 128 * ETDIM + t;
            #pragma unroll 8
            for (int k = 0; k < 128; ++k) acc += fl[k] * Wp[k * ETDIM];
            atomicAdd(&ws[OFF_ERAW + t], acc);
        }
    }
}

// ------ K6: E unpack + usage/alloc(rank-product) + write/memory/cr ---------
__global__ __launch_bounds__(512) void k6_small(
    const float* __restrict__ memory, const float* __restrict__ lrw,
    const float* __restrict__ lu, const float* __restrict__ lww,
    float* __restrict__ ws)
{
    const int t = threadIdx.x;
    const int lane = t & 63, wid = t >> 6;
    __shared__ float Es[400];
    __shared__ float rk[256], wk[32], er[32], wv[32], fgs[8], rs_s[8], rm[24], scal[3];
    __shared__ float u_s[512];
    __shared__ float wred[8];
    __shared__ float wred8[8][8];
    __shared__ float srk[8];

    if (t < ETDIM) Es[t] = ws[OFF_ERAW + t];
    __syncthreads();

    if (t < 256)                 rk[t] = Es[t];
    if (t >= 256 && t < 264)     rs_s[t - 256] = 1.f - log_sigmoid(Es[t]);
    if (t >= 264 && t < 296)     wk[t - 264] = Es[t];
    if (t == 296)                scal[0] = 1.f - log_sigmoid(Es[296]);   // write_strength
    if (t >= 297 && t < 329)     er[t - 297] = sigm(Es[t]);
    if (t >= 329 && t < 361)     wv[t - 329] = Es[t];
    if (t >= 361 && t < 369)     fgs[t - 361] = sigm(Es[t]);
    if (t == 369)                scal[1] = sigm(Es[369]);                // alloc_gate
    if (t == 370)                scal[2] = sigm(Es[370]);                // write_gate
    if (t >= 384 && t < 392) {                                          // read_modes
        int r = t - 384;
        float a = Es[371 + 3*r], b = Es[372 + 3*r], c = Es[373 + 3*r];
        float mx = fmaxf(a, fmaxf(b, c));
        float ea = expf(a - mx), eb = expf(b - mx), ec = expf(c - mx);
        float s = ea + eb + ec;
        rm[3*r] = ea / s; rm[3*r + 1] = eb / s; rm[3*r + 2] = ec / s;
    }
    __syncthreads();

    // usage
    float psi = 1.f;
    #pragma unroll
    for (int r = 0; r < 8; ++r) psi *= 1.f - fgs[r] * lrw[t * 8 + r];
    float ua = lu[t], ub = lww[t];
    float u_t = (ua + ub - ua * ub) * psi;
    u_s[t] = u_t;
    __syncthreads();

    // alloc[t] = (1-u_t) * prod over (u_j,j) lexicographically before (u_t,t)
    float prod = 1.f;
    for (int j = 0; j < 512; ++j) {
        float uj = u_s[j];
        bool before = (uj < u_t) || (uj == u_t && j < t);
        prod *= before ? uj : 1.f;
    }
    float alloc_t = (1.f - u_t) * prod;

    // write-key norm (every thread, broadcast reads)
    float s2 = 0.f;
    #pragma unroll
    for (int w = 0; w < 32; ++w) s2 += wk[w] * wk[w];
    float wkinv = 1.f / fmaxf(sqrtf(s2), EPSV);

    // content write score
    float mrow[32];
    float dotv = 0.f, nn = 0.f;
    #pragma unroll
    for (int w = 0; w < 32; ++w) {
        float m = memory[t * 32 + w];
        mrow[w] = m; dotv += m * wk[w]; nn += m * m;
    }
    float score = scal[0] * wkinv * dotv / fmaxf(sqrtf(nn), EPSV);
    float v = score;
    #pragma unroll
    for (int o = 32; o > 0; o >>= 1) v = fmaxf(v, __shfl_xor(v, o));
    if (lane == 0) wred[wid] = v;
    __syncthreads();
    float mx = wred[0];
    #pragma unroll
    for (int qq = 1; qq < 8; ++qq) mx = fmaxf(mx, wred[qq]);
    __syncthreads();
    float e = expf(score - mx);
    v = e;
    #pragma unroll
    for (int o = 32; o > 0; o >>= 1) v += __shfl_xor(v, o);
    if (lane == 0) wred[wid] = v;
    __syncthreads();
    float ssum = 0.f;
    #pragma unroll
    for (int qq = 0; qq < 8; ++qq) ssum += wred[qq];
    float cwv = e / ssum;

    float wwn = scal[2] * (scal[1] * alloc_t + (1.f - scal[1]) * cwv);
    ws[OFF_WW + t] = wwn;

    // memory_new + row norm
    float nn2 = 0.f;
    #pragma unroll
    for (int w = 0; w < 32; ++w) {
        float mn = mrow[w] * (1.f - wwn * er[w]) + wwn * wv[w];
        mrow[w] = mn; nn2 += mn * mn;
        ws[OFF_MEMNEW + t * 32 + w] = mn;
    }
    float inv2 = 1.f / fmaxf(sqrtf(nn2), EPSV);

    if (t < 8) {
        float s3 = 0.f;
        #pragma unroll
        for (int w = 0; w < 32; ++w) { float x = rk[w * 8 + t]; s3 += x * x; }
        srk[t] = rs_s[t] / fmaxf(sqrtf(s3), EPSV);
    }
    __syncthreads();

    // read content scores + softmax over n per head (shfl reductions)
    float sc[8];
    #pragma unroll
    for (int r = 0; r < 8; ++r) {
        float d2 = 0.f;
        #pragma unroll
        for (int w = 0; w < 32; ++w) d2 += mrow[w] * rk[w * 8 + r];
        sc[r] = srk[r] * inv2 * d2;
    }
    #pragma unroll
    for (int r = 0; r < 8; ++r) {
        float x = sc[r];
        #pragma unroll
        for (int o = 32; o > 0; o >>= 1) x = fmaxf(x, __shfl_xor(x, o));
        if (lane == 0) wred8[wid][r] = x;
    }
    __syncthreads();
    float mxr[8];
    #pragma unroll
    for (int r = 0; r < 8; ++r) {
        float m = wred8[0][r];
        #pragma unroll
        for (int qq = 1; qq < 8; ++qq) m = fmaxf(m, wred8[qq][r]);
        mxr[r] = m;
    }
    __syncthreads();
    float ex[8];
    #pragma unroll
    for (int r = 0; r < 8; ++r) {
        ex[r] = expf(sc[r] - mxr[r]);
        float x = ex[r];
        #pragma unroll
        for (int o = 32; o > 0; o >>= 1) x += __shfl_xor(x, o);
        if (lane == 0) wred8[wid][r] = x;
    }
    __syncthreads();
    #pragma unroll
    for (int r = 0; r < 8; ++r) {
        float sm = 0.f;
        #pragma unroll
        for (int qq = 0; qq < 8; ++qq) sm += wred8[qq][r];
        ws[OFF_CR + t * 8 + r] = ex[r] / sm;
    }
    if (t < 24) ws[OFF_RM + t] = rm[t];
}

// ---------------- K7: linkage fw/bw ---------------------------------------
__global__ __launch_bounds__(256) void k7_linkage(
    const float* __restrict__ linkage, const float* __restrict__ prec,
    const float* __restrict__ lrw, float* __restrict__ ws)
{
    __shared__ float lrw_s[4096];
    __shared__ float ww_s[512];
    __shared__ float red2[2048];
    const int t = threadIdx.x, blk = blockIdx.x;
    for (int i = t; i < 4096; i += 256) lrw_s[i] = lrw[i];
    for (int i = t; i < 512; i += 256)  ww_s[i] = ws[OFF_WW + i];
    __syncthreads();

    if (blk < 512) {
        const int i = blk;
        const float ww_i = ww_s[i];
        float facc[8] = {0,0,0,0,0,0,0,0};
        for (int j = t; j < 512; j += 256) {
            float Lm = (j == i) ? 0.f
                     : (1.f - ww_i - ww_s[j]) * linkage[(size_t)i * 512 + j] + ww_i * prec[j];
            #pragma unroll
            for (int r = 0; r < 8; ++r) facc[r] += Lm * lrw_s[j * 8 + r];
        }
        #pragma unroll
        for (int r = 0; r < 8; ++r) red2[t * 8 + r] = facc[r];
        __syncthreads();
        for (int s = 128; s > 0; s >>= 1) {
            if (t < s) {
                #pragma unroll
                for (int r = 0; r < 8; ++r) red2[t * 8 + r] += red2[(t + s) * 8 + r];
            }
            __syncthreads();
        }
        if (t < 8) ws[OFF_FW + i * 8 + t] = red2[t];
    } else {
        const int bb = blk - 512;
        const int ii = t & 63, p = t >> 6;
        const int i = bb * 64 + ii;
        const float ww_i = ww_s[i], prec_i = prec[i];
        float bacc[8] = {0,0,0,0,0,0,0,0};
        for (int j = p * 128; j < p * 128 + 128; ++j) {
            float lj  = linkage[(size_t)j * 512 + i];
            float wwj = ww_s[j];
            float Lm  = (j == i) ? 0.f : (1.f - wwj - ww_i) * lj + wwj * prec_i;
            #pragma unroll
            for (int r = 0; r < 8; ++r) bacc[r] += Lm * lrw_s[j * 8 + r];
        }
        #pragma unroll
        for (int r = 0; r < 8; ++r) red2[t * 8 + r] = bacc[r];
        __syncthreads();
        if (p == 0) {
            #pragma unroll
            for (int r = 0; r < 8; ++r) {
                float s = red2[t * 8 + r] + red2[(t + 64) * 8 + r]
                        + red2[(t + 128) * 8 + r] + red2[(t + 192) * 8 + r];
                ws[OFF_BW + i * 8 + r] = s;
            }
        }
    }
}

// ------- K8: rw -> rv (in-LDS, per-block) -> y += rv @ W_r -----------------
__global__ __launch_bounds__(256) void k8_read_out(
    const float* __restrict__ Wr, float* __restrict__ dout,
    const float* __restrict__ ws)
{
    __shared__ float mn_s[NDIM * 32];     // 64 KB
    __shared__ float rw_s[NDIM * 8];      // 16 KB
    __shared__ float rred[8][32][8];      // 8 KB
    __shared__ float rv_s[256];
    __shared__ float rm_s[24];
    const int t = threadIdx.x;

    for (int i = t; i < NDIM * 8; i += 256)   // 16384 floats as float4
        *reinterpret_cast<float4*>(mn_s + (i << 2)) =
            *reinterpret_cast<const float4*>(ws + OFF_MEMNEW + (i << 2));
    if (t < 24) rm_s[t] = ws[OFF_RM + t];
    __syncthreads();

    for (int idx = t; idx < 4096; idx += 256) {
        int r = idx & 7;
        rw_s[idx] = ws[OFF_BW + idx] * rm_s[r * 3]
                  + ws[OFF_CR + idx] * rm_s[r * 3 + 1]
                  + ws[OFF_FW + idx] * rm_s[r * 3 + 2];
    }
    __syncthreads();

    const int g = t >> 5, w = t & 31;
    float acc[8] = {0,0,0,0,0,0,0,0};
    for (int n = g * 64; n < g * 64 + 64; ++n) {
        float m = mn_s[n * 32 + w];
        #pragma unroll
        for (int r = 0; r < 8; ++r) acc[r] += m * rw_s[n * 8 + r];
    }
    #pragma unroll
    for (int r = 0; r < 8; ++r) rred[g][w][r] = acc[r];
    __syncthreads();
    {
        int w2 = t >> 3, r2 = t & 7;
        float s = 0.f;
        #pragma unroll
        for (int qq = 0; qq < 8; ++qq) s += rred[qq][w2][r2];
        rv_s[w2 * 8 + r2] = s;
    }
    __syncthreads();

    int v = blockIdx.x * 256 + t;
    if (v < VTDIM) {
        float acc2 = 0.f;
        const float* Wp = Wr + v;
        #pragma unroll 8
        for (int k = 0; k < 256; ++k) acc2 += rv_s[k] * Wp[(size_t)k * VTDIM];
        dout[v] += acc2;
    }
}

extern "C" void kernel_launch(void* const* d_in, const int* in_sizes, int n_in,
                              void* d_out, int out_size, void* d_ws, size_t ws_size,
                              hipStream_t stream)
{
    const float* x_in   = (const float*)d_in[0];
    const float* Wi     = (const float*)d_in[1];
    const float* bi     = (const float*)d_in[2];
    const float* Wf     = (const float*)d_in[3];
    const float* bf     = (const float*)d_in[4];
    const float* Wo     = (const float*)d_in[5];
    const float* bo     = (const float*)d_in[6];
    const float* Wss    = (const float*)d_in[7];
    const float* bs     = (const float*)d_in[8];
    const float* Wy     = (const float*)d_in[9];
    const float* We     = (const float*)d_in[10];
    const float* Wr     = (const float*)d_in[11];
    const float* memory = (const float*)d_in[12];
    const float* lrv    = (const float*)d_in[13];
    const float* hprev  = (const float*)d_in[14];
    const float* old_st = (const float*)d_in[15];
    const float* prec   = (const float*)d_in[16];
    const float* linkage= (const float*)d_in[17];
    const float* lrw    = (const float*)d_in[18];
    const float* lu     = (const float*)d_in[19];
    const float* lww    = (const float*)d_in[20];
    float* out = (float*)d_out;
    float* ws  = (float*)d_ws;

    hipMemsetAsync((void*)(ws + OFF_FIXED), 0, 32 * HDIM * sizeof(float), stream);

    k1_partial<<<K1_COMPUTE + K1_COPYB, 256, 0, stream>>>(
        x_in, lrv, hprev, Wi, Wf, Wo, Wss, ws, out);
    k3_recurrent<<<1, 1024, 0, stream>>>(bi, bf, bo, bs, old_st, ws);
    k45_out_E<<<128, 256, 0, stream>>>(Wy, We, out, ws);
    k6_small<<<1, 512, 0, stream>>>(memory, lrw, lu, lww, ws);
    k7_linkage<<<520, 256, 0, stream>>>(linkage, prec, lrw, ws);
    k8_read_out<<<15, 256, 0, stream>>>(Wr, out, ws);
}

// Round 6
// 267.765 us; speedup vs baseline: 1.2924x; 1.2037x over previous
//
#include <hip/hip_runtime.h>
#include <math.h>

#define XDIM 47764
#define HDIM 128
#define LDIM 8
#define VTDIM 3620
#define WDIM 32
#define RDIM 8
#define NDIM 512
#define RW 256            // W*R
#define DDIM 48276        // X + RW + 2H
#define FIXED 48148       // X + RW + H (rows of si independent of h_prev_layer)
#define ETDIM 395
#define EPSV 1e-8f

#define CHUNK 768
#define NCHUNK 63         // ceil(48148/768)
#define K1_COMPUTE (32 * NCHUNK)   // 2016
#define K1_COPYB 128               // wrec copy blocks

// ws layout (float offsets)
#define OFF_FIXED   258048     // 32*128 gate preacts (atomic accum, memset 0)
#define OFF_WREC    262144     // 32*128*128 = 524288
#define OFF_FLAT    786432     // 1024
#define OFF_ERAW    787456     // 512
#define OFF_WW      787968     // 512
#define OFF_MEMNEW  788480     // 16384
#define OFF_CR      804864     // 4096
#define OFF_RM      808960     // 32
#define OFF_FW      808992     // 4096
#define OFF_BW      813088     // 4096
#define OFF_RV      817184     // 256

typedef float f4 __attribute__((ext_vector_type(4)));

__device__ __forceinline__ f4 ntload4(const float* p) {
    return __builtin_nontemporal_load((const f4*)p);
}

__device__ inline float sigm(float x) { return 1.f / (1.f + expf(-x)); }
__device__ inline float log_sigmoid(float x) {
    return (x >= 0.f) ? -log1pf(expf(-x)) : (x - log1pf(expf(x)));
}

// ---------------- K1: gate pre-activations (nontemporal) + weight compaction
__global__ __launch_bounds__(256) void k1_partial(
    const float* __restrict__ x_in, const float* __restrict__ lrv,
    const float* __restrict__ hprev,
    const float* __restrict__ Wi, const float* __restrict__ Wf,
    const float* __restrict__ Wo, const float* __restrict__ Ws,
    float* __restrict__ ws, float* __restrict__ out)
{
    const int bid = blockIdx.x;
    const int t   = threadIdx.x;

    if (bid >= K1_COMPUTE) {
        // compaction: W*[l][FIXED+j][h] -> wrec[combo][j][h]
        int cb = bid - K1_COMPUTE;
        #pragma unroll
        for (int r = 0; r < 4; ++r) {
            int idx4  = cb * 1024 + r * 256 + t;
            int flat  = idx4 << 2;
            int combo = flat >> 14;
            int rem   = flat & 16383;
            int j = rem >> 7, h = rem & 127;
            int g = combo >> 3, l = combo & 7;
            const float* Wg = (g == 0) ? Wi : (g == 1) ? Wf : (g == 2) ? Wo : Ws;
            float4 v = *reinterpret_cast<const float4*>(
                Wg + ((size_t)l * DDIM + FIXED + j) * HDIM + h);
            *reinterpret_cast<float4*>(ws + OFF_WREC + flat) = v;
        }
        if (cb == 0) { ws[OFF_ERAW + t] = 0.f; ws[OFF_ERAW + 256 + t] = 0.f; }
        else if (cb == 1) {
            #pragma unroll
            for (int r = 0; r < 8; ++r) out[r * 256 + t] = 0.f;
        } else if (cb == 2) {
            #pragma unroll
            for (int r = 0; r < 7; ++r) {
                int v = 2048 + r * 256 + t;
                if (v < VTDIM) out[v] = 0.f;
            }
        }
        return;
    }

    const int combo = bid / NCHUNK;
    const int chunk = bid % NCHUNK;
    const int g = combo >> 3, l = combo & 7;
    const float* __restrict__ Wg = (g == 0) ? Wi : (g == 1) ? Wf : (g == 2) ? Wo : Ws;
    const int d0 = chunk * CHUNK;

    __shared__ float s_lds[CHUNK];
    for (int i = t; i < CHUNK; i += 256) {
        int d = d0 + i;
        float v = 0.f;
        if (d < XDIM)            v = x_in[d];
        else if (d < XDIM + RW)  v = lrv[d - XDIM];
        else if (d < FIXED)      v = hprev[l * HDIM + (d - XDIM - RW)];
        s_lds[i] = v;
    }
    __syncthreads();

    const int c4 = t & 15;    // float4 column -> cols c4 and c4+16
    const int p  = t >> 4;    // row slice 0..15, each 48 contiguous rows
    const int r0 = p * 48;
    const float* wp = Wg + ((size_t)l * DDIM + d0 + r0) * HDIM + (c4 << 2);

    f4 a = {0.f, 0.f, 0.f, 0.f};
    f4 b = {0.f, 0.f, 0.f, 0.f};

    if (chunk != NCHUNK - 1) {
        #pragma unroll 4
        for (int i = 0; i < 48; ++i) {
            float s = s_lds[r0 + i];
            const f4 w0 = ntload4(wp);
            const f4 w1 = ntload4(wp + 64);
            wp += HDIM;
            a += s * w0;
            b += s * w1;
        }
    } else {
        for (int i = 0; i < 48; ++i) {
            if (d0 + r0 + i >= FIXED) break;
            float s = s_lds[r0 + i];
            const f4 w0 = ntload4(wp);
            const f4 w1 = ntload4(wp + 64);
            wp += HDIM;
            a += s * w0;
            b += s * w1;
        }
    }

    __shared__ f4 red[16][32];
    red[p][c4]      = a;
    red[p][c4 + 16] = b;
    __syncthreads();
    if (t < 32) {
        f4 s = red[0][t];
        #pragma unroll
        for (int q = 1; q < 16; ++q) s += red[q][t];
        float* fx = ws + OFF_FIXED + combo * HDIM + (t << 2);
        atomicAdd(fx + 0, s.x);
        atomicAdd(fx + 1, s.y);
        atomicAdd(fx + 2, s.z);
        atomicAdd(fx + 3, s.w);
    }
}

// -------- K3: bias + sequential layer chain (1 block) ----------------------
__global__ __launch_bounds__(1024) void k3_recurrent(
    const float* __restrict__ bi, const float* __restrict__ bf,
    const float* __restrict__ bo, const float* __restrict__ bs,
    const float* __restrict__ old_states, float* __restrict__ ws)
{
    const int t = threadIdx.x;          // 0..1023
    const int g = t >> 8;               // gate 0..3
    const int q = (t >> 7) & 1;         // half of j-dim
    const int h = t & 127;

    __shared__ float hp[128];
    __shared__ float gl[4][2][128];

    float fx[8];
    const float* bg = (g == 0) ? bi : (g == 1) ? bf : (g == 2) ? bo : bs;
    if (q == 0) {
        #pragma unroll
        for (int l = 0; l < LDIM; ++l)
            fx[l] = ws[OFF_FIXED + (g * 8 + l) * HDIM + h] + bg[l * HDIM + h];
    }
    if (t < 128) hp[t] = 0.f;
    __syncthreads();

    for (int l = 0; l < LDIM; ++l) {
        int combo = g * 8 + l;
        float acc = (q == 0) ? fx[l] : 0.f;
        const float* wr = ws + OFF_WREC + (size_t)combo * 16384 + (q << 6) * 128 + h;
        #pragma unroll 8
        for (int j = 0; j < 64; ++j) acc += hp[(q << 6) + j] * wr[j * 128];
        gl[g][q][h] = acc;
        __syncthreads();
        if (t < 128) {
            float ig = sigm(gl[0][0][t] + gl[0][1][t]);
            float fg = sigm(gl[1][0][t] + gl[1][1][t]);
            float og = sigm(gl[2][0][t] + gl[2][1][t]);
            float ss = tanhf(gl[3][0][t] + gl[3][1][t]);
            float st = fg * old_states[l * HDIM + t] + ig * ss;
            float hn = og * tanhf(st);
            hp[t] = hn;
            ws[OFF_FLAT + l * HDIM + t] = hn;
        }
        __syncthreads();
    }
}

// ---------------- K45: flat@W_y -> d_out, flat@W_E -> E_raw ----------------
// Wy: 16 k-chunks of 64 x 15 v-tiles = 240 blocks; We: 8 k-chunks = 8 blocks
__global__ __launch_bounds__(256) void k45_out_E(
    const float* __restrict__ Wy, const float* __restrict__ We,
    float* __restrict__ dout, float* __restrict__ ws)
{
    const int blk = blockIdx.x, t = threadIdx.x;
    if (blk < 240) {
        int vt = blk % 15, kc = blk / 15;     // kc 0..15, 64 deep
        __shared__ float fl[64];
        if (t < 64) fl[t] = ws[OFF_FLAT + kc * 64 + t];
        __syncthreads();
        int v = vt * 256 + t;
        if (v < VTDIM) {
            float acc = 0.f;
            const float* Wp = Wy + (size_t)kc * 64 * VTDIM + v;
            #pragma unroll 8
            for (int k = 0; k < 64; ++k) acc += fl[k] * Wp[(size_t)k * VTDIM];
            atomicAdd(&dout[v], acc);
        }
    } else {
        int kc = blk - 240;                   // 0..7, 128 deep
        __shared__ float fl2[128];
        if (t < 128) fl2[t] = ws[OFF_FLAT + kc * 128 + t];
        __syncthreads();
        if (t < ETDIM) {
            float acc = 0.f;
            const float* Wp = We + (size_t)kc * 128 * ETDIM + t;
            #pragma unroll 8
            for (int k = 0; k < 128; ++k) acc += fl2[k] * Wp[k * ETDIM];
            atomicAdd(&ws[OFF_ERAW + t], acc);
        }
    }
}

// ------ K6: E unpack + usage/alloc(rank-product) + write/memory/cr ---------
__global__ __launch_bounds__(512) void k6_small(
    const float* __restrict__ memory, const float* __restrict__ lrw,
    const float* __restrict__ lu, const float* __restrict__ lww,
    float* __restrict__ ws)
{
    const int t = threadIdx.x;
    const int lane = t & 63, wid = t >> 6;
    __shared__ float Es[400];
    __shared__ float rk[256], wk[32], er[32], wv[32], fgs[8], rs_s[8], rm[24], scal[3];
    __shared__ float u_s[512];
    __shared__ float wred[8];
    __shared__ float wred8[8][8];
    __shared__ float srk[8];

    if (t < ETDIM) Es[t] = ws[OFF_ERAW + t];
    __syncthreads();

    if (t < 256)                 rk[t] = Es[t];
    if (t >= 256 && t < 264)     rs_s[t - 256] = 1.f - log_sigmoid(Es[t]);
    if (t >= 264 && t < 296)     wk[t - 264] = Es[t];
    if (t == 296)                scal[0] = 1.f - log_sigmoid(Es[296]);   // write_strength
    if (t >= 297 && t < 329)     er[t - 297] = sigm(Es[t]);
    if (t >= 329 && t < 361)     wv[t - 329] = Es[t];
    if (t >= 361 && t < 369)     fgs[t - 361] = sigm(Es[t]);
    if (t == 369)                scal[1] = sigm(Es[369]);                // alloc_gate
    if (t == 370)                scal[2] = sigm(Es[370]);                // write_gate
    if (t >= 384 && t < 392) {                                          // read_modes
        int r = t - 384;
        float a = Es[371 + 3*r], b = Es[372 + 3*r], c = Es[373 + 3*r];
        float mx = fmaxf(a, fmaxf(b, c));
        float ea = expf(a - mx), eb = expf(b - mx), ec = expf(c - mx);
        float s = ea + eb + ec;
        rm[3*r] = ea / s; rm[3*r + 1] = eb / s; rm[3*r + 2] = ec / s;
    }
    __syncthreads();

    // usage
    float psi = 1.f;
    #pragma unroll
    for (int r = 0; r < 8; ++r) psi *= 1.f - fgs[r] * lrw[t * 8 + r];
    float ua = lu[t], ub = lww[t];
    float u_t = (ua + ub - ua * ub) * psi;
    u_s[t] = u_t;
    __syncthreads();

    // alloc[t] = (1-u_t) * prod over (u_j,j) lexicographically before (u_t,t)
    float prod = 1.f;
    for (int j = 0; j < 512; ++j) {
        float uj = u_s[j];
        bool before = (uj < u_t) || (uj == u_t && j < t);
        prod *= before ? uj : 1.f;
    }
    float alloc_t = (1.f - u_t) * prod;

    // write-key norm (every thread, broadcast reads)
    float s2 = 0.f;
    #pragma unroll
    for (int w = 0; w < 32; ++w) s2 += wk[w] * wk[w];
    float wkinv = 1.f / fmaxf(sqrtf(s2), EPSV);

    // content write score
    float mrow[32];
    float dotv = 0.f, nn = 0.f;
    #pragma unroll
    for (int w = 0; w < 32; ++w) {
        float m = memory[t * 32 + w];
        mrow[w] = m; dotv += m * wk[w]; nn += m * m;
    }
    float score = scal[0] * wkinv * dotv / fmaxf(sqrtf(nn), EPSV);
    float v = score;
    #pragma unroll
    for (int o = 32; o > 0; o >>= 1) v = fmaxf(v, __shfl_xor(v, o));
    if (lane == 0) wred[wid] = v;
    __syncthreads();
    float mx = wred[0];
    #pragma unroll
    for (int qq = 1; qq < 8; ++qq) mx = fmaxf(mx, wred[qq]);
    __syncthreads();
    float e = expf(score - mx);
    v = e;
    #pragma unroll
    for (int o = 32; o > 0; o >>= 1) v += __shfl_xor(v, o);
    if (lane == 0) wred[wid] = v;
    __syncthreads();
    float ssum = 0.f;
    #pragma unroll
    for (int qq = 0; qq < 8; ++qq) ssum += wred[qq];
    float cwv = e / ssum;

    float wwn = scal[2] * (scal[1] * alloc_t + (1.f - scal[1]) * cwv);
    ws[OFF_WW + t] = wwn;

    // memory_new + row norm
    float nn2 = 0.f;
    #pragma unroll
    for (int w = 0; w < 32; ++w) {
        float mn = mrow[w] * (1.f - wwn * er[w]) + wwn * wv[w];
        mrow[w] = mn; nn2 += mn * mn;
        ws[OFF_MEMNEW + t * 32 + w] = mn;
    }
    float inv2 = 1.f / fmaxf(sqrtf(nn2), EPSV);

    if (t < 8) {
        float s3 = 0.f;
        #pragma unroll
        for (int w = 0; w < 32; ++w) { float x = rk[w * 8 + t]; s3 += x * x; }
        srk[t] = rs_s[t] / fmaxf(sqrtf(s3), EPSV);
    }
    __syncthreads();

    // read content scores + softmax over n per head (shfl reductions)
    float sc[8];
    #pragma unroll
    for (int r = 0; r < 8; ++r) {
        float d2 = 0.f;
        #pragma unroll
        for (int w = 0; w < 32; ++w) d2 += mrow[w] * rk[w * 8 + r];
        sc[r] = srk[r] * inv2 * d2;
    }
    #pragma unroll
    for (int r = 0; r < 8; ++r) {
        float x = sc[r];
        #pragma unroll
        for (int o = 32; o > 0; o >>= 1) x = fmaxf(x, __shfl_xor(x, o));
        if (lane == 0) wred8[wid][r] = x;
    }
    __syncthreads();
    float mxr[8];
    #pragma unroll
    for (int r = 0; r < 8; ++r) {
        float m = wred8[0][r];
        #pragma unroll
        for (int qq = 1; qq < 8; ++qq) m = fmaxf(m, wred8[qq][r]);
        mxr[r] = m;
    }
    __syncthreads();
    float ex[8];
    #pragma unroll
    for (int r = 0; r < 8; ++r) {
        ex[r] = expf(sc[r] - mxr[r]);
        float x = ex[r];
        #pragma unroll
        for (int o = 32; o > 0; o >>= 1) x += __shfl_xor(x, o);
        if (lane == 0) wred8[wid][r] = x;
    }
    __syncthreads();
    #pragma unroll
    for (int r = 0; r < 8; ++r) {
        float sm = 0.f;
        #pragma unroll
        for (int qq = 0; qq < 8; ++qq) sm += wred8[qq][r];
        ws[OFF_CR + t * 8 + r] = ex[r] / sm;
    }
    if (t < 24) ws[OFF_RM + t] = rm[t];
}

// ---------------- K7: linkage fw/bw ---------------------------------------
__global__ __launch_bounds__(256) void k7_linkage(
    const float* __restrict__ linkage, const float* __restrict__ prec,
    const float* __restrict__ lrw, float* __restrict__ ws)
{
    __shared__ float lrw_s[4096];
    __shared__ float ww_s[512];
    __shared__ float red2[2048];
    const int t = threadIdx.x, blk = blockIdx.x;
    for (int i = t; i < 4096; i += 256) lrw_s[i] = lrw[i];
    for (int i = t; i < 512; i += 256)  ww_s[i] = ws[OFF_WW + i];
    __syncthreads();

    if (blk < 512) {
        const int i = blk;
        const float ww_i = ww_s[i];
        float facc[8] = {0,0,0,0,0,0,0,0};
        for (int j = t; j < 512; j += 256) {
            float Lm = (j == i) ? 0.f
                     : (1.f - ww_i - ww_s[j]) * linkage[(size_t)i * 512 + j] + ww_i * prec[j];
            #pragma unroll
            for (int r = 0; r < 8; ++r) facc[r] += Lm * lrw_s[j * 8 + r];
        }
        #pragma unroll
        for (int r = 0; r < 8; ++r) red2[t * 8 + r] = facc[r];
        __syncthreads();
        for (int s = 128; s > 0; s >>= 1) {
            if (t < s) {
                #pragma unroll
                for (int r = 0; r < 8; ++r) red2[t * 8 + r] += red2[(t + s) * 8 + r];
            }
            __syncthreads();
        }
        if (t < 8) ws[OFF_FW + i * 8 + t] = red2[t];
    } else {
        const int bb = blk - 512;
        const int ii = t & 63, p = t >> 6;
        const int i = bb * 64 + ii;
        const float ww_i = ww_s[i], prec_i = prec[i];
        float bacc[8] = {0,0,0,0,0,0,0,0};
        for (int j = p * 128; j < p * 128 + 128; ++j) {
            float lj  = linkage[(size_t)j * 512 + i];
            float wwj = ww_s[j];
            float Lm  = (j == i) ? 0.f : (1.f - wwj - ww_i) * lj + wwj * prec_i;
            #pragma unroll
            for (int r = 0; r < 8; ++r) bacc[r] += Lm * lrw_s[j * 8 + r];
        }
        #pragma unroll
        for (int r = 0; r < 8; ++r) red2[t * 8 + r] = bacc[r];
        __syncthreads();
        if (p == 0) {
            #pragma unroll
            for (int r = 0; r < 8; ++r) {
                float s = red2[t * 8 + r] + red2[(t + 64) * 8 + r]
                        + red2[(t + 128) * 8 + r] + red2[(t + 192) * 8 + r];
                ws[OFF_BW + i * 8 + r] = s;
            }
        }
    }
}

// ---------------- K8a: rw -> rv (1 block) ----------------------------------
__global__ __launch_bounds__(256) void k8a_rv(float* __restrict__ ws)
{
    __shared__ float mn_s[NDIM * 32];     // 64 KB
    __shared__ float rw_s[NDIM * 8];      // 16 KB
    __shared__ float rred[8][32][8];      // 8 KB
    __shared__ float rm_s[24];
    const int t = threadIdx.x;

    for (int i = t; i < NDIM * 8; i += 256)   // 16384 floats as float4
        *reinterpret_cast<float4*>(mn_s + (i << 2)) =
            *reinterpret_cast<const float4*>(ws + OFF_MEMNEW + (i << 2));
    if (t < 24) rm_s[t] = ws[OFF_RM + t];
    __syncthreads();

    for (int idx = t; idx < 4096; idx += 256) {
        int r = idx & 7;
        rw_s[idx] = ws[OFF_BW + idx] * rm_s[r * 3]
                  + ws[OFF_CR + idx] * rm_s[r * 3 + 1]
                  + ws[OFF_FW + idx] * rm_s[r * 3 + 2];
    }
    __syncthreads();

    const int g = t >> 5, w = t & 31;
    float acc[8] = {0,0,0,0,0,0,0,0};
    for (int n = g * 64; n < g * 64 + 64; ++n) {
        float m = mn_s[n * 32 + w];
        #pragma unroll
        for (int r = 0; r < 8; ++r) acc[r] += m * rw_s[n * 8 + r];
    }
    #pragma unroll
    for (int r = 0; r < 8; ++r) rred[g][w][r] = acc[r];
    __syncthreads();
    {
        int w2 = t >> 3, r2 = t & 7;
        float s = 0.f;
        #pragma unroll
        for (int qq = 0; qq < 8; ++qq) s += rred[qq][w2][r2];
        ws[OFF_RV + w2 * 8 + r2] = s;
    }
}

// ---------------- K8b: y += rv @ W_r (60 blocks: 4 kc x 15 vt) --------------
__global__ __launch_bounds__(256) void k8b_wr(
    const float* __restrict__ Wr, float* __restrict__ dout,
    const float* __restrict__ ws)
{
    const int blk = blockIdx.x, t = threadIdx.x;
    const int vt = blk % 15, kc = blk / 15;     // kc 0..3, 64 deep
    __shared__ float rv_s[64];
    if (t < 64) rv_s[t] = ws[OFF_RV + kc * 64 + t];
    __syncthreads();
    int v = vt * 256 + t;
    if (v < VTDIM) {
        float acc = 0.f;
        const float* Wp = Wr + (size_t)kc * 64 * VTDIM + v;
        #pragma unroll 8
        for (int k = 0; k < 64; ++k) acc += rv_s[k] * Wp[(size_t)k * VTDIM];
        atomicAdd(&dout[v], acc);
    }
}

extern "C" void kernel_launch(void* const* d_in, const int* in_sizes, int n_in,
                              void* d_out, int out_size, void* d_ws, size_t ws_size,
                              hipStream_t stream)
{
    const float* x_in   = (const float*)d_in[0];
    const float* Wi     = (const float*)d_in[1];
    const float* bi     = (const float*)d_in[2];
    const float* Wf     = (const float*)d_in[3];
    const float* bf     = (const float*)d_in[4];
    const float* Wo     = (const float*)d_in[5];
    const float* bo     = (const float*)d_in[6];
    const float* Wss    = (const float*)d_in[7];
    const float* bs     = (const float*)d_in[8];
    const float* Wy     = (const float*)d_in[9];
    const float* We     = (const float*)d_in[10];
    const float* Wr     = (const float*)d_in[11];
    const float* memory = (const float*)d_in[12];
    const float* lrv    = (const float*)d_in[13];
    const float* hprev  = (const float*)d_in[14];
    const float* old_st = (const float*)d_in[15];
    const float* prec   = (const float*)d_in[16];
    const float* linkage= (const float*)d_in[17];
    const float* lrw    = (const float*)d_in[18];
    const float* lu     = (const float*)d_in[19];
    const float* lww    = (const float*)d_in[20];
    float* out = (float*)d_out;
    float* ws  = (float*)d_ws;

    hipMemsetAsync((void*)(ws + OFF_FIXED), 0, 32 * HDIM * sizeof(float), stream);

    k1_partial<<<K1_COMPUTE + K1_COPYB, 256, 0, stream>>>(
        x_in, lrv, hprev, Wi, Wf, Wo, Wss, ws, out);
    k3_recurrent<<<1, 1024, 0, stream>>>(bi, bf, bo, bs, old_st, ws);
    k45_out_E<<<248, 256, 0, stream>>>(Wy, We, out, ws);
    k6_small<<<1, 512, 0, stream>>>(memory, lrw, lu, lww, ws);
    k7_linkage<<<520, 256, 0, stream>>>(linkage, prec, lrw, ws);
    k8a_rv<<<1, 256, 0, stream>>>(ws);
    k8b_wr<<<60, 256, 0, stream>>>(Wr, out, ws);
}